// Round 14
// baseline (296.698 us; speedup 1.0000x reference)
//
#include <hip/hip_runtime.h>

#define HIDDEN 2048
#define SEQ    2048
#define BATCH  2
#define NHEAD  16
#define HDIM   128

typedef __attribute__((ext_vector_type(4))) int    i32x4;
typedef __attribute__((ext_vector_type(4))) float  f32x4;
typedef __attribute__((ext_vector_type(8))) __bf16 bf16x8;

__device__ __forceinline__ unsigned short f2bf(float f) {
    return __builtin_bit_cast(unsigned short, (__bf16)f);   // hw RNE cvt
}
__device__ __forceinline__ float bf2f(unsigned short h) {
    unsigned u = ((unsigned)h) << 16;
    return __builtin_bit_cast(float, u);
}
// async global->LDS, 16B per lane; dest must be wave-uniform base + lane*16
__device__ __forceinline__ void gl_lds16(const unsigned short* g, unsigned short* l) {
    __builtin_amdgcn_global_load_lds(
        (const __attribute__((address_space(1))) unsigned int*)g,
        (__attribute__((address_space(3))) unsigned int*)l, 16, 0, 0);
}

// ---------------- RoPE tables: ctab/stab[t*64 + i] = cos/sin(t * 10000^(-i/64))
__global__ void k_rope_tables(float* __restrict__ ctab, float* __restrict__ stab) {
    int idx = blockIdx.x * 256 + threadIdx.x;      // exactly SEQ*64 threads
    int t = idx >> 6, i = idx & 63;
    float inv = expf(-(float)i * 0.14391156831212793f);  // ln(10000)/64
    float ang = (float)t * inv;
    ctab[idx] = cosf(ang);
    stab[idx] = sinf(ang);
}

// ---------------- fp32 -> bf16 convert (4 elems/thread)
__global__ void k_cvt_bf16(const float* __restrict__ in, unsigned short* __restrict__ out, int n4) {
    int idx = blockIdx.x * blockDim.x + threadIdx.x;
    if (idx < n4) {
        float4 v = ((const float4*)in)[idx];
        ushort4 o;
        o.x = f2bf(v.x); o.y = f2bf(v.y); o.z = f2bf(v.z); o.w = f2bf(v.w);
        ((ushort4*)out)[idx] = o;
    }
}

// ---------------- W (K x N fp32) -> W^T (N x K bf16); z==0 (Wq) pre-scaled by
// log2(e)/sqrt(D) so softmax runs in exp2 domain (scale commutes with X@Wq, RoPE)
__global__ void k_transcvt4(const float* __restrict__ W0, const float* __restrict__ W1,
                            const float* __restrict__ W2, const float* __restrict__ W3,
                            unsigned short* __restrict__ O0, unsigned short* __restrict__ O1,
                            unsigned short* __restrict__ O2, unsigned short* __restrict__ O3) {
    __shared__ float tile[32][33];
    int z = blockIdx.z;
    const float* in = (z == 0) ? W0 : (z == 1) ? W1 : (z == 2) ? W2 : W3;
    unsigned short* out = (z == 0) ? O0 : (z == 1) ? O1 : (z == 2) ? O2 : O3;
    float scl = (z == 0) ? 0.12751743f : 1.0f;
    int tx = threadIdx.x, ty = threadIdx.y;
    int x = blockIdx.x * 32 + tx, y0 = blockIdx.y * 32;
#pragma unroll
    for (int i = 0; i < 4; i++)
        tile[ty + i * 8][tx] = in[(size_t)(y0 + ty + i * 8) * HIDDEN + x];
    __syncthreads();
    int x2 = blockIdx.y * 32 + tx, y2 = blockIdx.x * 32;
#pragma unroll
    for (int i = 0; i < 4; i++)
        out[(size_t)(y2 + ty + i * 8) * HIDDEN + x2] = f2bf(tile[tx][ty + i * 8] * scl);
}

// ---------------- 256x128-tile bf16 GEMM, 8 waves x (64x64), triple-buffer LDS.
// 2-phase K-step (T3+T4): each phase = {ds_read subtile; stage 3 loads; [vmcnt(6)];
// bar; 16-MFMA cluster; bar}. Single vmcnt per K-tile certifies tile t+1 (staged
// a full tile earlier -> 4-7 phases latency cover). R9 staging/swizzle unchanged.
template <int OUTB>
__global__ __launch_bounds__(512, 1) void k_gemm256(
    const unsigned short* __restrict__ A,
    const unsigned short* __restrict__ B0, const unsigned short* __restrict__ B1,
    const unsigned short* __restrict__ B2,
    void* __restrict__ C0, void* __restrict__ C1, void* __restrict__ C2,
    int K)
{
    __shared__ __align__(16) unsigned short S[3 * 24576];   // 144 KB
    const int nwg = gridDim.x;                               // 768 or 256, %8==0
    int id = blockIdx.x;
    int wg = (id & 7) * (nwg >> 3) + (id >> 3);              // XCD-aware swizzle (T1)
    const int z = wg >> 8;                                   // 16x16 blocks per z
    const int my = (wg >> 4) & 15, nx = wg & 15;
    const unsigned short* Bm = (z == 0) ? B0 : (z == 1 ? B1 : B2);
    void* Cv = (z == 0) ? C0 : (z == 1 ? C1 : C2);
    const int m0 = my * 256, n0 = nx * 128;
    const int tid = threadIdx.x, l = tid & 63, w = tid >> 6;
    const int wm = w >> 1, wn = w & 1;                       // 4 M-waves x 2 N-waves
    const int lr = l & 15, lg = l >> 4;

    const unsigned short* sg[6];
    int so[6];
#pragma unroll
    for (int j = 0; j < 4; j++) {
        int c = tid + j * 512, row = c >> 3, k8 = c & 7;
        sg[j] = A + (size_t)(m0 + row) * K + ((k8 ^ (row & 7)) * 8);
        so[j] = row * 64 + k8 * 8;
    }
#pragma unroll
    for (int j = 0; j < 2; j++) {
        int c = tid + j * 512, row = c >> 3, k8 = c & 7;
        sg[4 + j] = Bm + (size_t)(n0 + row) * K + ((k8 ^ (row & 7)) * 8);
        so[4 + j] = 16384 + row * 64 + k8 * 8;
    }

    f32x4 acc[4][4] = {};

    auto stage6 = [&](int t) {          // prologue only: all 6 chunks
        unsigned short* buf = &S[(t % 3) * 24576];
        const int ko = t * 64;
#pragma unroll
        for (int j = 0; j < 6; j++) gl_lds16(sg[j] + ko, &buf[so[j]]);
    };
    auto stageH = [&](int t, int h) {   // half h: {sg0,sg1,sg4} or {sg2,sg3,sg5}
        unsigned short* buf = &S[(t % 3) * 24576];
        const int ko = t * 64;
        gl_lds16(sg[h * 2] + ko,     &buf[so[h * 2]]);
        gl_lds16(sg[h * 2 + 1] + ko, &buf[so[h * 2 + 1]]);
        gl_lds16(sg[4 + h] + ko,     &buf[so[4 + h]]);
    };

    const int nt = K / 64;                 // 32
    stage6(0); stage6(1);                  // 12 loads in flight
    asm volatile("s_waitcnt vmcnt(6)" ::: "memory");   // certify tile 0
    __builtin_amdgcn_s_barrier();
    __builtin_amdgcn_sched_barrier(0);

    for (int t = 0; t < nt; ++t) {
        const unsigned short* buf = &S[(t % 3) * 24576];
        const unsigned short* bb = buf + 16384;
        const int xk0 = (lg ^ (lr & 7)) * 8, xk1 = ((4 + lg) ^ (lr & 7)) * 8;
        i32x4 af0[2], af1[2], bf0[4], bf1[4];

        // ---------- phase 0: A rows i=0,1 x full B
#pragma unroll
        for (int i = 0; i < 2; i++) {
            int R = (wm * 64 + i * 16 + lr) * 64;
            af0[i] = *(const i32x4*)&buf[R + xk0];
            af1[i] = *(const i32x4*)&buf[R + xk1];
        }
#pragma unroll
        for (int j = 0; j < 4; j++) {
            int R = (wn * 64 + j * 16 + lr) * 64;
            bf0[j] = *(const i32x4*)&bb[R + xk0];
            bf1[j] = *(const i32x4*)&bb[R + xk1];
        }
        if (t + 2 < nt) stageH(t + 2, 0);
        __builtin_amdgcn_s_barrier();
        __builtin_amdgcn_sched_barrier(0);
        __builtin_amdgcn_s_setprio(1);
#pragma unroll
        for (int i = 0; i < 2; i++)
#pragma unroll
            for (int j = 0; j < 4; j++) {
                acc[i][j] = __builtin_amdgcn_mfma_f32_16x16x32_bf16(
                    __builtin_bit_cast(bf16x8, af0[i]),
                    __builtin_bit_cast(bf16x8, bf0[j]), acc[i][j], 0, 0, 0);
                acc[i][j] = __builtin_amdgcn_mfma_f32_16x16x32_bf16(
                    __builtin_bit_cast(bf16x8, af1[i]),
                    __builtin_bit_cast(bf16x8, bf1[j]), acc[i][j], 0, 0, 0);
            }
        __builtin_amdgcn_s_setprio(0);
        __builtin_amdgcn_s_barrier();

        // ---------- phase 1: A rows i=2,3 x full B (B frags persist in regs)
#pragma unroll
        for (int i = 0; i < 2; i++) {
            int R = (wm * 64 + (2 + i) * 16 + lr) * 64;
            af0[i] = *(const i32x4*)&buf[R + xk0];
            af1[i] = *(const i32x4*)&buf[R + xk1];
        }
        if (t + 2 < nt) {
            stageH(t + 2, 1);
            asm volatile("s_waitcnt vmcnt(6)" ::: "memory");   // certify tile t+1
        } else {
            asm volatile("s_waitcnt vmcnt(0)" ::: "memory");   // tail drain (old loads)
        }
        __builtin_amdgcn_s_barrier();
        __builtin_amdgcn_sched_barrier(0);
        __builtin_amdgcn_s_setprio(1);
#pragma unroll
        for (int i = 0; i < 2; i++)
#pragma unroll
            for (int j = 0; j < 4; j++) {
                acc[2 + i][j] = __builtin_amdgcn_mfma_f32_16x16x32_bf16(
                    __builtin_bit_cast(bf16x8, af0[i]),
                    __builtin_bit_cast(bf16x8, bf0[j]), acc[2 + i][j], 0, 0, 0);
                acc[2 + i][j] = __builtin_amdgcn_mfma_f32_16x16x32_bf16(
                    __builtin_bit_cast(bf16x8, af1[i]),
                    __builtin_bit_cast(bf16x8, bf1[j]), acc[2 + i][j], 0, 0, 0);
            }
        __builtin_amdgcn_s_setprio(0);
        __builtin_amdgcn_s_barrier();
    }

#pragma unroll
    for (int i = 0; i < 4; i++)
#pragma unroll
        for (int j = 0; j < 4; j++)
#pragma unroll
            for (int r = 0; r < 4; r++) {
                int m = m0 + wm * 64 + i * 16 + lg * 4 + r;
                int n = n0 + wn * 64 + j * 16 + lr;
                float v = acc[i][j][r];
                if (OUTB) ((unsigned short*)Cv)[(size_t)m * 2048 + n] = f2bf(v);
                else      ((float*)Cv)[(size_t)m * 2048 + n] = v;
            }
}

// ---------------- RoPE in-place on Q,K (pure rotation; Q's scale pre-folded in WqT)
__global__ void k_rope(unsigned short* __restrict__ Q, unsigned short* __restrict__ Kb,
                       const float* __restrict__ ctab, const float* __restrict__ stab)
{
    const int tid = threadIdx.x, l = tid & 63, w = tid >> 6;
    int hr = blockIdx.x * 4 + w;                 // head-row id, one wave each
    unsigned short* X = blockIdx.y ? Kb : Q;
    int bt = hr >> 4, h = hr & 15, t = bt & (SEQ - 1);
    size_t base = (size_t)bt * HIDDEN + h * HDIM;
    int d0 = l * 2;
    ushort2 xv = *(const ushort2*)&X[base + d0];
    float x0 = bf2f(xv.x), x1 = bf2f(xv.y);
    float prev = __shfl(x1, (l + 63) & 63);      // x[d0-1], lane0 wraps to x[127]
    int i0 = d0 & 63, i1 = (d0 + 1) & 63;
    float c0 = ctab[t * 64 + i0], s0 = stab[t * 64 + i0];
    float c1 = ctab[t * 64 + i1], s1 = stab[t * 64 + i1];
    ushort2 ov;
    ov.x = f2bf(x0 * c0 + prev * s0);
    ov.y = f2bf(x1 * c1 + x0 * s1);
    *(ushort2*)&X[base + d0] = ov;
}

// ---------------- V[bt][h*128+d] -> Vt[bh][d][t]  (per-(b,h) transpose)
__global__ void k_vtrans(const unsigned short* __restrict__ V, unsigned short* __restrict__ Vt)
{
    __shared__ unsigned short tile[32][33];
    int z = blockIdx.z;                     // bh
    int b = z >> 4, h = z & 15;
    int tx = threadIdx.x, ty = threadIdx.y;
    int d0 = blockIdx.x * 32, t0 = blockIdx.y * 32;
    const size_t ibase = (size_t)b * SEQ * HIDDEN + h * HDIM;
#pragma unroll
    for (int i = 0; i < 4; i++)
        tile[ty + i * 8][tx] = V[ibase + (size_t)(t0 + ty + i * 8) * HIDDEN + d0 + tx];
    __syncthreads();
    const size_t obase = (size_t)z * HDIM * SEQ;
#pragma unroll
    for (int i = 0; i < 4; i++)
        Vt[obase + (size_t)(d0 + ty + i * 8) * SEQ + t0 + tx] = tile[tx][ty + i * 8];
}

// ---------------- flash attention: swapped-QK^T, 8 waves x 32 q-rows = 256 q/block.
// [R13-proven: attn ~88us, out of top-5] kf/vf fragments reused for both q-halves.
__global__ __launch_bounds__(512) void k_attn(
    const unsigned short* __restrict__ Q, const unsigned short* __restrict__ K,
    const unsigned short* __restrict__ Vt, unsigned short* __restrict__ ctx)
{
    __shared__ __align__(16) unsigned short Klds[2][64 * 128];   // 32 KB
    __shared__ __align__(16) unsigned short Vlds[2][128 * 64];   // 32 KB
    __shared__ __align__(16) unsigned short Plds[8][32 * 64];    // 32 KB
    const int tid = threadIdx.x, l = tid & 63, w = tid >> 6;     // 8 waves
    const int lr = l & 15, lg = l >> 4;
    const int bid = blockIdx.x;                 // 256 blocks, 1D
    const int sX = bid >> 3;                    // 0..31
    const int bh = (bid & 7) * 4 + (sX >> 3);   // XCD (bid&7) owns heads 4k..4k+3
    const int q0 = (sX & 7) * 256;
    const int b = bh >> 4, h = bh & 15;

    // Q fragments: 2 q-halves x 4 K-chunks (rows q0+w*32+qh*16+lr)
    i32x4 qf[2][4];
#pragma unroll
    for (int qh = 0; qh < 2; qh++) {
        const unsigned short* qbase =
            Q + (size_t)(b * SEQ + q0 + w * 32 + qh * 16 + lr) * HIDDEN + h * HDIM + lg * 8;
#pragma unroll
        for (int c = 0; c < 4; c++) qf[qh][c] = *(const i32x4*)(qbase + c * 32);
    }

    // staging: 2 K-chunks + 2 V-chunks per thread (512 threads), source pre-swizzled
    const unsigned short* kg[2];
    const unsigned short* vg[2];
    int kl[2], vl[2];
#pragma unroll
    for (int c = 0; c < 2; c++) {
        int cc = tid + c * 512;
        {   int row = cc >> 4, ch = cc & 15, sch = ch ^ (row & 7);
            kg[c] = K + (size_t)(b * SEQ + row) * HIDDEN + h * HDIM + sch * 8;
            kl[c] = cc * 8; }
        {   int row = cc >> 3, ch = cc & 7, sch = ch ^ (row & 7);
            vg[c] = Vt + (size_t)(bh * HDIM + row) * SEQ + sch * 8;
            vl[c] = cc * 8; }
    }

    auto stage = [&](int t, int bsel) {
        const size_t ko = (size_t)t * 64;
#pragma unroll
        for (int c = 0; c < 2; c++) {
            gl_lds16(kg[c] + ko * HIDDEN, &Klds[bsel][kl[c]]);
            gl_lds16(vg[c] + ko,          &Vlds[bsel][vl[c]]);
        }
    };

    f32x4 acc[2][8] = {};
    float m_run[2] = {-1e30f, -1e30f}, l_run[2] = {0.f, 0.f};

    stage(0, 0);
    const int nt = SEQ / 64;                // 32
    for (int t = 0; t < nt; ++t) {
        asm volatile("s_waitcnt vmcnt(0)" ::: "memory");
        __builtin_amdgcn_s_barrier();           // tile t staged, prev reads retired
        asm volatile("" ::: "memory");
        __builtin_amdgcn_sched_barrier(0);
        if (t + 1 < nt) stage(t + 1, (t + 1) & 1);
        const unsigned short* Kb_ = Klds[t & 1];
        const unsigned short* Vb_ = Vlds[t & 1];

        // swapped QK^T: kf loaded once per (ks,c), reused for both q-halves
        f32x4 s[4][2];
        __builtin_amdgcn_s_setprio(1);
#pragma unroll
        for (int ks = 0; ks < 4; ks++) {
            s[ks][0] = f32x4{0.f, 0.f, 0.f, 0.f};
            s[ks][1] = f32x4{0.f, 0.f, 0.f, 0.f};
#pragma unroll
            for (int c = 0; c < 4; c++) {
                i32x4 kf = *(const i32x4*)&Kb_[(ks * 16 + lr) * 128 + ((c * 4 + lg) ^ (lr & 7)) * 8];
                s[ks][0] = __builtin_amdgcn_mfma_f32_16x16x32_bf16(
                    __builtin_bit_cast(bf16x8, kf), __builtin_bit_cast(bf16x8, qf[0][c]),
                    s[ks][0], 0, 0, 0);
                s[ks][1] = __builtin_amdgcn_mfma_f32_16x16x32_bf16(
                    __builtin_bit_cast(bf16x8, kf), __builtin_bit_cast(bf16x8, qf[1][c]),
                    s[ks][1], 0, 0, 0);
            }
        }
        __builtin_amdgcn_s_setprio(0);

        // lane-local row softmax per q-half (exp2 domain; scale folded into WqT)
        float p[2][4][4];
        float fac[2];
        bool need_any = false;
#pragma unroll
        for (int qh = 0; qh < 2; qh++) {
            float mx0 = fmaxf(fmaxf(s[0][qh][0], s[0][qh][1]), fmaxf(s[0][qh][2], s[0][qh][3]));
            float mx1 = fmaxf(fmaxf(s[1][qh][0], s[1][qh][1]), fmaxf(s[1][qh][2], s[1][qh][3]));
            float mx2 = fmaxf(fmaxf(s[2][qh][0], s[2][qh][1]), fmaxf(s[2][qh][2], s[2][qh][3]));
            float mx3 = fmaxf(fmaxf(s[3][qh][0], s[3][qh][1]), fmaxf(s[3][qh][2], s[3][qh][3]));
            float pmax = fmaxf(fmaxf(mx0, mx1), fmaxf(mx2, mx3));
            pmax = fmaxf(pmax, __shfl_xor(pmax, 16));
            pmax = fmaxf(pmax, __shfl_xor(pmax, 32));
            bool need = pmax > m_run[qh] + 8.0f;     // defer-rescale (T13)
            fac[qh] = need ? __builtin_amdgcn_exp2f(m_run[qh] - pmax) : 1.0f;
            float mn = need ? pmax : m_run[qh];
            m_run[qh] = mn;
            float psum = 0.f;
#pragma unroll
            for (int ks = 0; ks < 4; ks++) {
                float e0 = __builtin_amdgcn_exp2f(s[ks][qh][0] - mn);
                float e1 = __builtin_amdgcn_exp2f(s[ks][qh][1] - mn);
                float e2 = __builtin_amdgcn_exp2f(s[ks][qh][2] - mn);
                float e3 = __builtin_amdgcn_exp2f(s[ks][qh][3] - mn);
                p[qh][ks][0] = e0; p[qh][ks][1] = e1;
                p[qh][ks][2] = e2; p[qh][ks][3] = e3;
                psum += (e0 + e1) + (e2 + e3);
            }
            psum += __shfl_xor(psum, 16);
            psum += __shfl_xor(psum, 32);
            l_run[qh] = l_run[qh] * fac[qh] + psum;
            need_any |= need;
        }

        // P -> wave-private LDS (involution swizzle, R12-verified mapping)
        unsigned short* pw = &Plds[w][0];
#pragma unroll
        for (int qh = 0; qh < 2; qh++)
#pragma unroll
            for (int ks = 0; ks < 4; ks++) {
                ushort4 pk;
                pk.x = f2bf(p[qh][ks][0]); pk.y = f2bf(p[qh][ks][1]);
                pk.z = f2bf(p[qh][ks][2]); pk.w = f2bf(p[qh][ks][3]);
                int chunk = ks * 2 + (lg >> 1);
                *(ushort4*)&pw[(qh * 16 + lr) * 64 + ((chunk ^ (lr & 7)) * 8) + (lg & 1) * 4] = pk;
            }

        if (__any((int)need_any)) {
#pragma unroll
            for (int qh = 0; qh < 2; qh++) {
                float facq[4];
#pragma unroll
                for (int r = 0; r < 4; r++) facq[r] = __shfl(fac[qh], lg * 4 + r);
#pragma unroll
                for (int db = 0; db < 8; db++)
#pragma unroll
                    for (int r = 0; r < 4; r++) acc[qh][db][r] *= facq[r];
            }
        }

        __builtin_amdgcn_s_setprio(1);
#pragma unroll
        for (int kk = 0; kk < 2; kk++) {
            i32x4 pf0 = *(const i32x4*)&pw[(lr) * 64 + ((kk * 4 + lg) ^ (lr & 7)) * 8];
            i32x4 pf1 = *(const i32x4*)&pw[(16 + lr) * 64 + ((kk * 4 + lg) ^ (lr & 7)) * 8];
#pragma unroll
            for (int db = 0; db < 8; db++) {
                i32x4 vf = *(const i32x4*)&Vb_[(db * 16 + lr) * 64 + ((kk * 4 + lg) ^ (lr & 7)) * 8];
                acc[0][db] = __builtin_amdgcn_mfma_f32_16x16x32_bf16(
                    __builtin_bit_cast(bf16x8, pf0), __builtin_bit_cast(bf16x8, vf),
                    acc[0][db], 0, 0, 0);
                acc[1][db] = __builtin_amdgcn_mfma_f32_16x16x32_bf16(
                    __builtin_bit_cast(bf16x8, pf1), __builtin_bit_cast(bf16x8, vf),
                    acc[1][db], 0, 0, 0);
            }
        }
        __builtin_amdgcn_s_setprio(0);
    }

#pragma unroll
    for (int qh = 0; qh < 2; qh++) {
        float inv[4];
#pragma unroll
        for (int r = 0; r < 4; r++) inv[r] = 1.0f / __shfl(l_run[qh], lg * 4 + r);
#pragma unroll
        for (int db = 0; db < 8; db++)
#pragma unroll
            for (int r = 0; r < 4; r++) {
                int trow = q0 + w * 32 + qh * 16 + lg * 4 + r;
                ctx[(size_t)(b * SEQ + trow) * HIDDEN + h * HDIM + db * 16 + lr] =
                    f2bf(acc[qh][db][r] * inv[r]);
            }
    }
}

extern "C" void kernel_launch(void* const* d_in, const int* in_sizes, int n_in,
                              void* d_out, int out_size, void* d_ws, size_t ws_size,
                              hipStream_t stream)
{
    (void)in_sizes; (void)n_in; (void)out_size; (void)ws_size;
    const float* X  = (const float*)d_in[0];
    const float* Wq = (const float*)d_in[1];
    const float* Wk = (const float*)d_in[2];
    const float* Wv = (const float*)d_in[3];
    const float* Wo = (const float*)d_in[4];
    float* out = (float*)d_out;
    char* ws = (char*)d_ws;

    unsigned short* Xb  = (unsigned short*)(ws);                 // 16 MB  (4096x2048 bf16)
    unsigned short* WqT = (unsigned short*)(ws + 16777216);      // 8 MB each, N x K bf16
    unsigned short* WkT = (unsigned short*)(ws + 25165824);
    unsigned short* WvT = (unsigned short*)(ws + 33554432);
    unsigned short* WoT = (unsigned short*)(ws + 41943040);
    unsigned short* Qb  = (unsigned short*)(ws + 50331648);      // 16 MB each
    unsigned short* Kb  = (unsigned short*)(ws + 67108864);
    unsigned short* Vb  = (unsigned short*)(ws + 83886080);
    unsigned short* Vt  = (unsigned short*)(ws + 100663296);
    unsigned short* Cx  = (unsigned short*)(ws + 117440512);
    float* ctab = (float*)(ws + 134217728);                      // 0.5 MB each
    float* stab = (float*)(ws + 134742016);

    k_rope_tables<<<512, 256, 0, stream>>>(ctab, stab);
    k_cvt_bf16<<<8192, 256, 0, stream>>>(X, Xb, 2097152);
    k_transcvt4<<<dim3(64, 64, 4), dim3(32, 8), 0, stream>>>(Wq, Wk, Wv, Wo,
                                                             WqT, WkT, WvT, WoT);
    k_gemm256<1><<<768, 512, 0, stream>>>(Xb, WqT, WkT, WvT, Qb, Kb, Vb, 2048);
    k_rope<<<dim3(16384, 2), 256, 0, stream>>>(Qb, Kb, ctab, stab);
    k_vtrans<<<dim3(4, 64, 32), dim3(32, 8), 0, stream>>>(Vb, Vt);
    k_attn<<<256, 512, 0, stream>>>(Qb, Kb, Vt, Cx);
    k_gemm256<0><<<256, 512, 0, stream>>>(Cx, WoT, WoT, WoT, out, out, out, 2048);
}

// Round 15
// 279.497 us; speedup vs baseline: 1.0615x; 1.0615x over previous
//
#include <hip/hip_runtime.h>

#define HIDDEN 2048
#define SEQ    2048
#define BATCH  2
#define NHEAD  16
#define HDIM   128

typedef __attribute__((ext_vector_type(4))) int    i32x4;
typedef __attribute__((ext_vector_type(4))) float  f32x4;
typedef __attribute__((ext_vector_type(8))) __bf16 bf16x8;

__device__ __forceinline__ unsigned short f2bf(float f) {
    return __builtin_bit_cast(unsigned short, (__bf16)f);   // hw RNE cvt
}
__device__ __forceinline__ float bf2f(unsigned short h) {
    unsigned u = ((unsigned)h) << 16;
    return __builtin_bit_cast(float, u);
}
// async global->LDS, 16B per lane; dest must be wave-uniform base + lane*16
__device__ __forceinline__ void gl_lds16(const unsigned short* g, unsigned short* l) {
    __builtin_amdgcn_global_load_lds(
        (const __attribute__((address_space(1))) unsigned int*)g,
        (__attribute__((address_space(3))) unsigned int*)l, 16, 0, 0);
}

// ---------------- RoPE tables: ctab/stab[t*64 + i] = cos/sin(t * 10000^(-i/64))
__global__ void k_rope_tables(float* __restrict__ ctab, float* __restrict__ stab) {
    int idx = blockIdx.x * 256 + threadIdx.x;      // exactly SEQ*64 threads
    int t = idx >> 6, i = idx & 63;
    float inv = expf(-(float)i * 0.14391156831212793f);  // ln(10000)/64
    float ang = (float)t * inv;
    ctab[idx] = cosf(ang);
    stab[idx] = sinf(ang);
}

// ---------------- fp32 -> bf16 convert (4 elems/thread)
__global__ void k_cvt_bf16(const float* __restrict__ in, unsigned short* __restrict__ out, int n4) {
    int idx = blockIdx.x * blockDim.x + threadIdx.x;
    if (idx < n4) {
        float4 v = ((const float4*)in)[idx];
        ushort4 o;
        o.x = f2bf(v.x); o.y = f2bf(v.y); o.z = f2bf(v.z); o.w = f2bf(v.w);
        ((ushort4*)out)[idx] = o;
    }
}

// ---------------- W (K x N fp32) -> W^T (N x K bf16); z==0 (Wq) pre-scaled by
// log2(e)/sqrt(D) so softmax runs in exp2 domain (scale commutes with X@Wq, RoPE)
__global__ void k_transcvt4(const float* __restrict__ W0, const float* __restrict__ W1,
                            const float* __restrict__ W2, const float* __restrict__ W3,
                            unsigned short* __restrict__ O0, unsigned short* __restrict__ O1,
                            unsigned short* __restrict__ O2, unsigned short* __restrict__ O3) {
    __shared__ float tile[32][33];
    int z = blockIdx.z;
    const float* in = (z == 0) ? W0 : (z == 1) ? W1 : (z == 2) ? W2 : W3;
    unsigned short* out = (z == 0) ? O0 : (z == 1) ? O1 : (z == 2) ? O2 : O3;
    float scl = (z == 0) ? 0.12751743f : 1.0f;
    int tx = threadIdx.x, ty = threadIdx.y;
    int x = blockIdx.x * 32 + tx, y0 = blockIdx.y * 32;
#pragma unroll
    for (int i = 0; i < 4; i++)
        tile[ty + i * 8][tx] = in[(size_t)(y0 + ty + i * 8) * HIDDEN + x];
    __syncthreads();
    int x2 = blockIdx.y * 32 + tx, y2 = blockIdx.x * 32;
#pragma unroll
    for (int i = 0; i < 4; i++)
        out[(size_t)(y2 + ty + i * 8) * HIDDEN + x2] = f2bf(tile[tx][ty + i * 8] * scl);
}

// ---------------- 256x128-tile bf16 GEMM, 8 waves x (64x64), triple-buffer LDS,
// counted vmcnt(6)  [R9-proven: 112us QKV, MfmaUtil 38.8%, 0 bank conflicts].
// z==2 (V) epilogue writes DIRECTLY TRANSPOSED into Vt[bh][d][t] (fuses k_vtrans):
// acc[i][j][r] has r = 4 consecutive tokens -> one aligned ushort4 per (i,j).
template <int OUTB>
__global__ __launch_bounds__(512, 1) void k_gemm256(
    const unsigned short* __restrict__ A,
    const unsigned short* __restrict__ B0, const unsigned short* __restrict__ B1,
    const unsigned short* __restrict__ B2,
    void* __restrict__ C0, void* __restrict__ C1, void* __restrict__ C2,
    int K)
{
    __shared__ __align__(16) unsigned short S[3 * 24576];   // 144 KB
    const int nwg = gridDim.x;                               // 768 or 256, %8==0
    int id = blockIdx.x;
    int wg = (id & 7) * (nwg >> 3) + (id >> 3);              // XCD-aware swizzle (T1)
    const int z = wg >> 8;                                   // 16x16 blocks per z
    const int my = (wg >> 4) & 15, nx = wg & 15;
    const unsigned short* Bm = (z == 0) ? B0 : (z == 1 ? B1 : B2);
    void* Cv = (z == 0) ? C0 : (z == 1 ? C1 : C2);
    const int m0 = my * 256, n0 = nx * 128;
    const int tid = threadIdx.x, l = tid & 63, w = tid >> 6;
    const int wm = w >> 1, wn = w & 1;                       // 4 M-waves x 2 N-waves
    const int lr = l & 15, lg = l >> 4;

    const unsigned short* sg[6];
    int so[6];
#pragma unroll
    for (int j = 0; j < 4; j++) {
        int c = tid + j * 512, row = c >> 3, k8 = c & 7;
        sg[j] = A + (size_t)(m0 + row) * K + ((k8 ^ (row & 7)) * 8);
        so[j] = row * 64 + k8 * 8;
    }
#pragma unroll
    for (int j = 0; j < 2; j++) {
        int c = tid + j * 512, row = c >> 3, k8 = c & 7;
        sg[4 + j] = Bm + (size_t)(n0 + row) * K + ((k8 ^ (row & 7)) * 8);
        so[4 + j] = 16384 + row * 64 + k8 * 8;
    }

    f32x4 acc[4][4] = {};

    auto stage = [&](int t) {
        unsigned short* buf = &S[(t % 3) * 24576];
        const int ko = t * 64;
#pragma unroll
        for (int j = 0; j < 6; j++) gl_lds16(sg[j] + ko, &buf[so[j]]);
    };
    auto compute = [&](int t) {
        const unsigned short* buf = &S[(t % 3) * 24576];
        const unsigned short* bb = buf + 16384;
        const int xk0 = (lg ^ (lr & 7)) * 8, xk1 = ((4 + lg) ^ (lr & 7)) * 8;
        i32x4 af0[4], af1[4], bf0[4], bf1[4];
#pragma unroll
        for (int i = 0; i < 4; i++) {
            int R = (wm * 64 + i * 16 + lr) * 64;
            af0[i] = *(const i32x4*)&buf[R + xk0];
            af1[i] = *(const i32x4*)&buf[R + xk1];
        }
#pragma unroll
        for (int j = 0; j < 4; j++) {
            int R = (wn * 64 + j * 16 + lr) * 64;
            bf0[j] = *(const i32x4*)&bb[R + xk0];
            bf1[j] = *(const i32x4*)&bb[R + xk1];
        }
        __builtin_amdgcn_s_setprio(1);
#pragma unroll
        for (int i = 0; i < 4; i++)
#pragma unroll
            for (int j = 0; j < 4; j++)
                acc[i][j] = __builtin_amdgcn_mfma_f32_16x16x32_bf16(
                    __builtin_bit_cast(bf16x8, af0[i]),
                    __builtin_bit_cast(bf16x8, bf0[j]), acc[i][j], 0, 0, 0);
#pragma unroll
        for (int i = 0; i < 4; i++)
#pragma unroll
            for (int j = 0; j < 4; j++)
                acc[i][j] = __builtin_amdgcn_mfma_f32_16x16x32_bf16(
                    __builtin_bit_cast(bf16x8, af1[i]),
                    __builtin_bit_cast(bf16x8, bf1[j]), acc[i][j], 0, 0, 0);
        __builtin_amdgcn_s_setprio(0);
    };

    const int nt = K / 64;                 // 32
    stage(0); stage(1);                    // 12 loads in flight
    for (int t = 0; t < nt - 1; ++t) {
        asm volatile("s_waitcnt vmcnt(6)" ::: "memory");
        __builtin_amdgcn_s_barrier();
        __builtin_amdgcn_sched_barrier(0);
        if (t < nt - 2) stage(t + 2);
        compute(t);
    }
    asm volatile("s_waitcnt vmcnt(0)" ::: "memory");
    __builtin_amdgcn_s_barrier();
    __builtin_amdgcn_sched_barrier(0);
    compute(nt - 1);

    if (OUTB && z == 2) {
        // V: write transposed Vt[(b*2048 + n)][t], t = m & 2047, b = m >> 11
        unsigned short* Vt = (unsigned short*)Cv;
        const int bb_ = m0 >> 11;
        const int tb = (m0 & 2047) + wm * 64;
#pragma unroll
        for (int i = 0; i < 4; i++)
#pragma unroll
            for (int j = 0; j < 4; j++) {
                int t0 = tb + i * 16 + lg * 4;
                int n = n0 + wn * 64 + j * 16 + lr;
                ushort4 pk;
                pk.x = f2bf(acc[i][j][0]); pk.y = f2bf(acc[i][j][1]);
                pk.z = f2bf(acc[i][j][2]); pk.w = f2bf(acc[i][j][3]);
                *(ushort4*)&Vt[((size_t)(bb_ * 2048 + n)) * 2048 + t0] = pk;
            }
    } else {
#pragma unroll
        for (int i = 0; i < 4; i++)
#pragma unroll
            for (int j = 0; j < 4; j++)
#pragma unroll
                for (int r = 0; r < 4; r++) {
                    int m = m0 + wm * 64 + i * 16 + lg * 4 + r;
                    int n = n0 + wn * 64 + j * 16 + lr;
                    float v = acc[i][j][r];
                    if (OUTB) ((unsigned short*)Cv)[(size_t)m * 2048 + n] = f2bf(v);
                    else      ((float*)Cv)[(size_t)m * 2048 + n] = v;
                }
    }
}

// ---------------- RoPE in-place on Q,K (pure rotation; Q's scale pre-folded in WqT)
__global__ void k_rope(unsigned short* __restrict__ Q, unsigned short* __restrict__ Kb,
                       const float* __restrict__ ctab, const float* __restrict__ stab)
{
    const int tid = threadIdx.x, l = tid & 63, w = tid >> 6;
    int hr = blockIdx.x * 4 + w;                 // head-row id, one wave each
    unsigned short* X = blockIdx.y ? Kb : Q;
    int bt = hr >> 4, h = hr & 15, t = bt & (SEQ - 1);
    size_t base = (size_t)bt * HIDDEN + h * HDIM;
    int d0 = l * 2;
    ushort2 xv = *(const ushort2*)&X[base + d0];
    float x0 = bf2f(xv.x), x1 = bf2f(xv.y);
    float prev = __shfl(x1, (l + 63) & 63);      // x[d0-1], lane0 wraps to x[127]
    int i0 = d0 & 63, i1 = (d0 + 1) & 63;
    float c0 = ctab[t * 64 + i0], s0 = stab[t * 64 + i0];
    float c1 = ctab[t * 64 + i1], s1 = stab[t * 64 + i1];
    ushort2 ov;
    ov.x = f2bf(x0 * c0 + prev * s0);
    ov.y = f2bf(x1 * c1 + x0 * s1);
    *(ushort2*)&X[base + d0] = ov;
}

// ---------------- flash attention: swapped-QK^T, 8 waves x 32 q-rows = 256 q/block.
// [R13-proven: attn ~88us] kf/vf fragments reused for both q-halves.
__global__ __launch_bounds__(512) void k_attn(
    const unsigned short* __restrict__ Q, const unsigned short* __restrict__ K,
    const unsigned short* __restrict__ Vt, unsigned short* __restrict__ ctx)
{
    __shared__ __align__(16) unsigned short Klds[2][64 * 128];   // 32 KB
    __shared__ __align__(16) unsigned short Vlds[2][128 * 64];   // 32 KB
    __shared__ __align__(16) unsigned short Plds[8][32 * 64];    // 32 KB
    const int tid = threadIdx.x, l = tid & 63, w = tid >> 6;     // 8 waves
    const int lr = l & 15, lg = l >> 4;
    const int bid = blockIdx.x;                 // 256 blocks, 1D
    const int sX = bid >> 3;                    // 0..31
    const int bh = (bid & 7) * 4 + (sX >> 3);   // XCD (bid&7) owns heads 4k..4k+3
    const int q0 = (sX & 7) * 256;
    const int b = bh >> 4, h = bh & 15;

    // Q fragments: 2 q-halves x 4 K-chunks (rows q0+w*32+qh*16+lr)
    i32x4 qf[2][4];
#pragma unroll
    for (int qh = 0; qh < 2; qh++) {
        const unsigned short* qbase =
            Q + (size_t)(b * SEQ + q0 + w * 32 + qh * 16 + lr) * HIDDEN + h * HDIM + lg * 8;
#pragma unroll
        for (int c = 0; c < 4; c++) qf[qh][c] = *(const i32x4*)(qbase + c * 32);
    }

    // staging: 2 K-chunks + 2 V-chunks per thread (512 threads), source pre-swizzled
    const unsigned short* kg[2];
    const unsigned short* vg[2];
    int kl[2], vl[2];
#pragma unroll
    for (int c = 0; c < 2; c++) {
        int cc = tid + c * 512;
        {   int row = cc >> 4, ch = cc & 15, sch = ch ^ (row & 7);
            kg[c] = K + (size_t)(b * SEQ + row) * HIDDEN + h * HDIM + sch * 8;
            kl[c] = cc * 8; }
        {   int row = cc >> 3, ch = cc & 7, sch = ch ^ (row & 7);
            vg[c] = Vt + (size_t)(bh * HDIM + row) * SEQ + sch * 8;
            vl[c] = cc * 8; }
    }

    auto stage = [&](int t, int bsel) {
        const size_t ko = (size_t)t * 64;
#pragma unroll
        for (int c = 0; c < 2; c++) {
            gl_lds16(kg[c] + ko * HIDDEN, &Klds[bsel][kl[c]]);
            gl_lds16(vg[c] + ko,          &Vlds[bsel][vl[c]]);
        }
    };

    f32x4 acc[2][8] = {};
    float m_run[2] = {-1e30f, -1e30f}, l_run[2] = {0.f, 0.f};

    stage(0, 0);
    const int nt = SEQ / 64;                // 32
    for (int t = 0; t < nt; ++t) {
        asm volatile("s_waitcnt vmcnt(0)" ::: "memory");
        __builtin_amdgcn_s_barrier();           // tile t staged, prev reads retired
        asm volatile("" ::: "memory");
        __builtin_amdgcn_sched_barrier(0);
        if (t + 1 < nt) stage(t + 1, (t + 1) & 1);
        const unsigned short* Kb_ = Klds[t & 1];
        const unsigned short* Vb_ = Vlds[t & 1];

        // swapped QK^T: kf loaded once per (ks,c), reused for both q-halves
        f32x4 s[4][2];
        __builtin_amdgcn_s_setprio(1);
#pragma unroll
        for (int ks = 0; ks < 4; ks++) {
            s[ks][0] = f32x4{0.f, 0.f, 0.f, 0.f};
            s[ks][1] = f32x4{0.f, 0.f, 0.f, 0.f};
#pragma unroll
            for (int c = 0; c < 4; c++) {
                i32x4 kf = *(const i32x4*)&Kb_[(ks * 16 + lr) * 128 + ((c * 4 + lg) ^ (lr & 7)) * 8];
                s[ks][0] = __builtin_amdgcn_mfma_f32_16x16x32_bf16(
                    __builtin_bit_cast(bf16x8, kf), __builtin_bit_cast(bf16x8, qf[0][c]),
                    s[ks][0], 0, 0, 0);
                s[ks][1] = __builtin_amdgcn_mfma_f32_16x16x32_bf16(
                    __builtin_bit_cast(bf16x8, kf), __builtin_bit_cast(bf16x8, qf[1][c]),
                    s[ks][1], 0, 0, 0);
            }
        }
        __builtin_amdgcn_s_setprio(0);

        // lane-local row softmax per q-half (exp2 domain; scale folded into WqT)
        float p[2][4][4];
        float fac[2];
        bool need_any = false;
#pragma unroll
        for (int qh = 0; qh < 2; qh++) {
            float mx0 = fmaxf(fmaxf(s[0][qh][0], s[0][qh][1]), fmaxf(s[0][qh][2], s[0][qh][3]));
            float mx1 = fmaxf(fmaxf(s[1][qh][0], s[1][qh][1]), fmaxf(s[1][qh][2], s[1][qh][3]));
            float mx2 = fmaxf(fmaxf(s[2][qh][0], s[2][qh][1]), fmaxf(s[2][qh][2], s[2][qh][3]));
            float mx3 = fmaxf(fmaxf(s[3][qh][0], s[3][qh][1]), fmaxf(s[3][qh][2], s[3][qh][3]));
            float pmax = fmaxf(fmaxf(mx0, mx1), fmaxf(mx2, mx3));
            pmax = fmaxf(pmax, __shfl_xor(pmax, 16));
            pmax = fmaxf(pmax, __shfl_xor(pmax, 32));
            bool need = pmax > m_run[qh] + 8.0f;     // defer-rescale (T13)
            fac[qh] = need ? __builtin_amdgcn_exp2f(m_run[qh] - pmax) : 1.0f;
            float mn = need ? pmax : m_run[qh];
            m_run[qh] = mn;
            float psum = 0.f;
#pragma unroll
            for (int ks = 0; ks < 4; ks++) {
                float e0 = __builtin_amdgcn_exp2f(s[ks][qh][0] - mn);
                float e1 = __builtin_amdgcn_exp2f(s[ks][qh][1] - mn);
                float e2 = __builtin_amdgcn_exp2f(s[ks][qh][2] - mn);
                float e3 = __builtin_amdgcn_exp2f(s[ks][qh][3] - mn);
                p[qh][ks][0] = e0; p[qh][ks][1] = e1;
                p[qh][ks][2] = e2; p[qh][ks][3] = e3;
                psum += (e0 + e1) + (e2 + e3);
            }
            psum += __shfl_xor(psum, 16);
            psum += __shfl_xor(psum, 32);
            l_run[qh] = l_run[qh] * fac[qh] + psum;
            need_any |= need;
        }

        // P -> wave-private LDS (involution swizzle, R12-verified mapping)
        unsigned short* pw = &Plds[w][0];
#pragma unroll
        for (int qh = 0; qh < 2; qh++)
#pragma unroll
            for (int ks = 0; ks < 4; ks++) {
                ushort4 pk;
                pk.x = f2bf(p[qh][ks][0]); pk.y = f2bf(p[qh][ks][1]);
                pk.z = f2bf(p[qh][ks][2]); pk.w = f2bf(p[qh][ks][3]);
                int chunk = ks * 2 + (lg >> 1);
                *(ushort4*)&pw[(qh * 16 + lr) * 64 + ((chunk ^ (lr & 7)) * 8) + (lg & 1) * 4] = pk;
            }

        if (__any((int)need_any)) {
#pragma unroll
            for (int qh = 0; qh < 2; qh++) {
                float facq[4];
#pragma unroll
                for (int r = 0; r < 4; r++) facq[r] = __shfl(fac[qh], lg * 4 + r);
#pragma unroll
                for (int db = 0; db < 8; db++)
#pragma unroll
                    for (int r = 0; r < 4; r++) acc[qh][db][r] *= facq[r];
            }
        }

        __builtin_amdgcn_s_setprio(1);
#pragma unroll
        for (int kk = 0; kk < 2; kk++) {
            i32x4 pf0 = *(const i32x4*)&pw[(lr) * 64 + ((kk * 4 + lg) ^ (lr & 7)) * 8];
            i32x4 pf1 = *(const i32x4*)&pw[(16 + lr) * 64 + ((kk * 4 + lg) ^ (lr & 7)) * 8];
#pragma unroll
            for (int db = 0; db < 8; db++) {
                i32x4 vf = *(const i32x4*)&Vb_[(db * 16 + lr) * 64 + ((kk * 4 + lg) ^ (lr & 7)) * 8];
                acc[0][db] = __builtin_amdgcn_mfma_f32_16x16x32_bf16(
                    __builtin_bit_cast(bf16x8, pf0), __builtin_bit_cast(bf16x8, vf),
                    acc[0][db], 0, 0, 0);
                acc[1][db] = __builtin_amdgcn_mfma_f32_16x16x32_bf16(
                    __builtin_bit_cast(bf16x8, pf1), __builtin_bit_cast(bf16x8, vf),
                    acc[1][db], 0, 0, 0);
            }
        }
        __builtin_amdgcn_s_setprio(0);
    }

#pragma unroll
    for (int qh = 0; qh < 2; qh++) {
        float inv[4];
#pragma unroll
        for (int r = 0; r < 4; r++) inv[r] = 1.0f / __shfl(l_run[qh], lg * 4 + r);
#pragma unroll
        for (int db = 0; db < 8; db++)
#pragma unroll
            for (int r = 0; r < 4; r++) {
                int trow = q0 + w * 32 + qh * 16 + lg * 4 + r;
                ctx[(size_t)(b * SEQ + trow) * HIDDEN + h * HDIM + db * 16 + lr] =
                    f2bf(acc[qh][db][r] * inv[r]);
            }
    }
}

extern "C" void kernel_launch(void* const* d_in, const int* in_sizes, int n_in,
                              void* d_out, int out_size, void* d_ws, size_t ws_size,
                              hipStream_t stream)
{
    (void)in_sizes; (void)n_in; (void)out_size; (void)ws_size;
    const float* X  = (const float*)d_in[0];
    const float* Wq = (const float*)d_in[1];
    const float* Wk = (const float*)d_in[2];
    const float* Wv = (const float*)d_in[3];
    const float* Wo = (const float*)d_in[4];
    float* out = (float*)d_out;
    char* ws = (char*)d_ws;

    unsigned short* Xb  = (unsigned short*)(ws);                 // 16 MB  (4096x2048 bf16)
    unsigned short* WqT = (unsigned short*)(ws + 16777216);      // 8 MB each, N x K bf16
    unsigned short* WkT = (unsigned short*)(ws + 25165824);
    unsigned short* WvT = (unsigned short*)(ws + 33554432);
    unsigned short* WoT = (unsigned short*)(ws + 41943040);
    unsigned short* Qb  = (unsigned short*)(ws + 50331648);      // 16 MB each
    unsigned short* Kb  = (unsigned short*)(ws + 67108864);
    unsigned short* Vt  = (unsigned short*)(ws + 100663296);     // V written transposed by GEMM
    unsigned short* Cx  = (unsigned short*)(ws + 117440512);
    float* ctab = (float*)(ws + 134217728);                      // 0.5 MB each
    float* stab = (float*)(ws + 134742016);

    k_rope_tables<<<512, 256, 0, stream>>>(ctab, stab);
    k_cvt_bf16<<<8192, 256, 0, stream>>>(X, Xb, 2097152);
    k_transcvt4<<<dim3(64, 64, 4), dim3(32, 8), 0, stream>>>(Wq, Wk, Wv, Wo,
                                                             WqT, WkT, WvT, WoT);
    k_gemm256<1><<<768, 512, 0, stream>>>(Xb, WqT, WkT, WvT, Qb, Kb, Vt, 2048);
    k_rope<<<dim3(16384, 2), 256, 0, stream>>>(Qb, Kb, ctab, stab);
    k_attn<<<256, 512, 0, stream>>>(Qb, Kb, Vt, Cx);
    k_gemm256<0><<<256, 512, 0, stream>>>(Cx, WoT, WoT, WoT, out, out, out, 2048);
}

// Round 16
// 261.419 us; speedup vs baseline: 1.1350x; 1.0692x over previous
//
#include <hip/hip_runtime.h>

#define HIDDEN 2048
#define SEQ    2048
#define BATCH  2
#define NHEAD  16
#define HDIM   128

typedef __attribute__((ext_vector_type(4))) int    i32x4;
typedef __attribute__((ext_vector_type(4))) float  f32x4;
typedef __attribute__((ext_vector_type(8))) __bf16 bf16x8;

__device__ __forceinline__ unsigned short f2bf(float f) {
    return __builtin_bit_cast(unsigned short, (__bf16)f);   // hw RNE cvt
}
__device__ __forceinline__ float bf2f(unsigned short h) {
    unsigned u = ((unsigned)h) << 16;
    return __builtin_bit_cast(float, u);
}
// async global->LDS, 16B per lane; dest must be wave-uniform base + lane*16
__device__ __forceinline__ void gl_lds16(const unsigned short* g, unsigned short* l) {
    __builtin_amdgcn_global_load_lds(
        (const __attribute__((address_space(1))) unsigned int*)g,
        (__attribute__((address_space(3))) unsigned int*)l, 16, 0, 0);
}

// ---------------- fp32 -> bf16 convert (blocks 0..8191) + RoPE tables (8192..8703)
__global__ void k_cvt_tables(const float* __restrict__ in, unsigned short* __restrict__ out,
                             float* __restrict__ ctab, float* __restrict__ stab) {
    int bid = blockIdx.x;
    if (bid < 8192) {
        int idx = bid * 256 + threadIdx.x;
        float4 v = ((const float4*)in)[idx];
        ushort4 o;
        o.x = f2bf(v.x); o.y = f2bf(v.y); o.z = f2bf(v.z); o.w = f2bf(v.w);
        ((ushort4*)out)[idx] = o;
    } else {
        int idx = (bid - 8192) * 256 + threadIdx.x;    // SEQ*64 entries
        int t = idx >> 6, i = idx & 63;
        float inv = expf(-(float)i * 0.14391156831212793f);  // ln(10000)/64
        float ang = (float)t * inv;
        ctab[idx] = cosf(ang);
        stab[idx] = sinf(ang);
    }
}

// ---------------- W (K x N fp32) -> W^T (N x K bf16); z==0 (Wq) pre-scaled by
// log2(e)/sqrt(D) so softmax runs in exp2 domain (scale commutes with X@Wq, RoPE)
__global__ void k_transcvt4(const float* __restrict__ W0, const float* __restrict__ W1,
                            const float* __restrict__ W2, const float* __restrict__ W3,
                            unsigned short* __restrict__ O0, unsigned short* __restrict__ O1,
                            unsigned short* __restrict__ O2, unsigned short* __restrict__ O3) {
    __shared__ float tile[32][33];
    int z = blockIdx.z;
    const float* in = (z == 0) ? W0 : (z == 1) ? W1 : (z == 2) ? W2 : W3;
    unsigned short* out = (z == 0) ? O0 : (z == 1) ? O1 : (z == 2) ? O2 : O3;
    float scl = (z == 0) ? 0.12751743f : 1.0f;
    int tx = threadIdx.x, ty = threadIdx.y;
    int x = blockIdx.x * 32 + tx, y0 = blockIdx.y * 32;
#pragma unroll
    for (int i = 0; i < 4; i++)
        tile[ty + i * 8][tx] = in[(size_t)(y0 + ty + i * 8) * HIDDEN + x];
    __syncthreads();
    int x2 = blockIdx.y * 32 + tx, y2 = blockIdx.x * 32;
#pragma unroll
    for (int i = 0; i < 4; i++)
        out[(size_t)(y2 + ty + i * 8) * HIDDEN + x2] = f2bf(tile[tx][ty + i * 8] * scl);
}

// ---------------- 256x128-tile bf16 GEMM, 8 waves x (64x64), triple-buffer LDS,
// counted vmcnt(6)  [R9-proven main loop: 0 bank conflicts, MfmaUtil 38.8%].
// Epilogues: z==2 writes V transposed into Vt[bh][d][t] (R15-proven);
// z<=1 (Q,K) apply RoPE in fp32 before the bf16 write (fuses k_rope):
//   prev[d-1] via lane shuffles; d-half boundary via 2KB LDS exchange (dead S buf0).
template <int OUTB>
__global__ __launch_bounds__(512, 1) void k_gemm256(
    const unsigned short* __restrict__ A,
    const unsigned short* __restrict__ B0, const unsigned short* __restrict__ B1,
    const unsigned short* __restrict__ B2,
    void* __restrict__ C0, void* __restrict__ C1, void* __restrict__ C2,
    const float* __restrict__ ctab, const float* __restrict__ stab,
    int K)
{
    __shared__ __align__(16) unsigned short S[3 * 24576];   // 144 KB
    const int nwg = gridDim.x;                               // 768 or 256, %8==0
    int id = blockIdx.x;
    int wg = (id & 7) * (nwg >> 3) + (id >> 3);              // XCD-aware swizzle (T1)
    const int z = wg >> 8;                                   // 16x16 blocks per z
    const int my = (wg >> 4) & 15, nx = wg & 15;
    const unsigned short* Bm = (z == 0) ? B0 : (z == 1 ? B1 : B2);
    void* Cv = (z == 0) ? C0 : (z == 1 ? C1 : C2);
    const int m0 = my * 256, n0 = nx * 128;
    const int tid = threadIdx.x, l = tid & 63, w = tid >> 6;
    const int wm = w >> 1, wn = w & 1;                       // 4 M-waves x 2 N-waves
    const int lr = l & 15, lg = l >> 4;

    const unsigned short* sg[6];
    int so[6];
#pragma unroll
    for (int j = 0; j < 4; j++) {
        int c = tid + j * 512, row = c >> 3, k8 = c & 7;
        sg[j] = A + (size_t)(m0 + row) * K + ((k8 ^ (row & 7)) * 8);
        so[j] = row * 64 + k8 * 8;
    }
#pragma unroll
    for (int j = 0; j < 2; j++) {
        int c = tid + j * 512, row = c >> 3, k8 = c & 7;
        sg[4 + j] = Bm + (size_t)(n0 + row) * K + ((k8 ^ (row & 7)) * 8);
        so[4 + j] = 16384 + row * 64 + k8 * 8;
    }

    f32x4 acc[4][4] = {};

    auto stage = [&](int t) {
        unsigned short* buf = &S[(t % 3) * 24576];
        const int ko = t * 64;
#pragma unroll
        for (int j = 0; j < 6; j++) gl_lds16(sg[j] + ko, &buf[so[j]]);
    };
    auto compute = [&](int t) {
        const unsigned short* buf = &S[(t % 3) * 24576];
        const unsigned short* bb = buf + 16384;
        const int xk0 = (lg ^ (lr & 7)) * 8, xk1 = ((4 + lg) ^ (lr & 7)) * 8;
        i32x4 af0[4], af1[4], bf0[4], bf1[4];
#pragma unroll
        for (int i = 0; i < 4; i++) {
            int R = (wm * 64 + i * 16 + lr) * 64;
            af0[i] = *(const i32x4*)&buf[R + xk0];
            af1[i] = *(const i32x4*)&buf[R + xk1];
        }
#pragma unroll
        for (int j = 0; j < 4; j++) {
            int R = (wn * 64 + j * 16 + lr) * 64;
            bf0[j] = *(const i32x4*)&bb[R + xk0];
            bf1[j] = *(const i32x4*)&bb[R + xk1];
        }
        __builtin_amdgcn_s_setprio(1);
#pragma unroll
        for (int i = 0; i < 4; i++)
#pragma unroll
            for (int j = 0; j < 4; j++)
                acc[i][j] = __builtin_amdgcn_mfma_f32_16x16x32_bf16(
                    __builtin_bit_cast(bf16x8, af0[i]),
                    __builtin_bit_cast(bf16x8, bf0[j]), acc[i][j], 0, 0, 0);
#pragma unroll
        for (int i = 0; i < 4; i++)
#pragma unroll
            for (int j = 0; j < 4; j++)
                acc[i][j] = __builtin_amdgcn_mfma_f32_16x16x32_bf16(
                    __builtin_bit_cast(bf16x8, af1[i]),
                    __builtin_bit_cast(bf16x8, bf1[j]), acc[i][j], 0, 0, 0);
        __builtin_amdgcn_s_setprio(0);
    };

    const int nt = K / 64;                 // 32
    stage(0); stage(1);                    // 12 loads in flight
    for (int t = 0; t < nt - 1; ++t) {
        asm volatile("s_waitcnt vmcnt(6)" ::: "memory");
        __builtin_amdgcn_s_barrier();
        __builtin_amdgcn_sched_barrier(0);
        if (t < nt - 2) stage(t + 2);
        compute(t);
    }
    asm volatile("s_waitcnt vmcnt(0)" ::: "memory");
    __builtin_amdgcn_s_barrier();
    __builtin_amdgcn_sched_barrier(0);
    compute(nt - 1);

    if (OUTB && z == 2) {
        // V: write transposed Vt[(b*2048 + n)][t], t = m & 2047, b = m >> 11
        unsigned short* Vt = (unsigned short*)Cv;
        const int bb_ = m0 >> 11;
        const int tb = (m0 & 2047) + wm * 64;
#pragma unroll
        for (int i = 0; i < 4; i++)
#pragma unroll
            for (int j = 0; j < 4; j++) {
                int t0 = tb + i * 16 + lg * 4;
                int n = n0 + wn * 64 + j * 16 + lr;
                ushort4 pk;
                pk.x = f2bf(acc[i][j][0]); pk.y = f2bf(acc[i][j][1]);
                pk.z = f2bf(acc[i][j][2]); pk.w = f2bf(acc[i][j][3]);
                *(ushort4*)&Vt[((size_t)(bb_ * 2048 + n)) * 2048 + t0] = pk;
            }
    } else if (OUTB) {
        // Q/K: fused RoPE.  d = wn*64 + j*16 + lr; prev = x[(d-1)&127]:
        //  lr>0: shfl(acc[i][j][r], l-1);  lr==0,j>0: shfl(acc[i][j-1][r], lg*16+15)
        //  lr==0,j==0: partner wave (wn^1) [i][3][r]@lr15 via LDS (d=127<->63 wrap)
        float* xch = (float*)S;        // 512 floats; buf0 reads retired pre-final-barrier
        if (lr == 15) {
#pragma unroll
            for (int i = 0; i < 4; i++)
#pragma unroll
                for (int r = 0; r < 4; r++)
                    xch[(((wm << 1) | wn) * 4 + i) * 16 + lg * 4 + r] = acc[i][3][r];
        }
        __syncthreads();
        unsigned short* Co = (unsigned short*)Cv;
#pragma unroll
        for (int i = 0; i < 4; i++)
#pragma unroll
            for (int r = 0; r < 4; r++) {
                int m = m0 + wm * 64 + i * 16 + lg * 4 + r;
                int t = m & 2047;
                float ldsprev = xch[(((wm << 1) | (wn ^ 1)) * 4 + i) * 16 + lg * 4 + r];
#pragma unroll
                for (int j = 0; j < 4; j++) {
                    float v = acc[i][j][r];
                    float pA = __shfl(v, l - 1);
                    float prev;
                    if (j == 0) {
                        prev = (lr == 0) ? ldsprev : pA;
                    } else {
                        float pB = __shfl(acc[i][j - 1][r], (l & 48) + 15);
                        prev = (lr == 0) ? pB : pA;
                    }
                    float cc = ctab[t * 64 + j * 16 + lr];
                    float ss = stab[t * 64 + j * 16 + lr];
                    int n = n0 + wn * 64 + j * 16 + lr;
                    Co[(size_t)m * 2048 + n] = f2bf(v * cc + prev * ss);
                }
            }
    } else {
#pragma unroll
        for (int i = 0; i < 4; i++)
#pragma unroll
            for (int j = 0; j < 4; j++)
#pragma unroll
                for (int r = 0; r < 4; r++) {
                    int m = m0 + wm * 64 + i * 16 + lg * 4 + r;
                    int n = n0 + wn * 64 + j * 16 + lr;
                    ((float*)Cv)[(size_t)m * 2048 + n] = acc[i][j][r];
                }
    }
}

// ---------------- flash attention: swapped-QK^T, 8 waves x 32 q-rows = 256 q/block.
// [R13-proven: attn ~88us] kf/vf fragments reused for both q-halves.
__global__ __launch_bounds__(512) void k_attn(
    const unsigned short* __restrict__ Q, const unsigned short* __restrict__ K,
    const unsigned short* __restrict__ Vt, unsigned short* __restrict__ ctx)
{
    __shared__ __align__(16) unsigned short Klds[2][64 * 128];   // 32 KB
    __shared__ __align__(16) unsigned short Vlds[2][128 * 64];   // 32 KB
    __shared__ __align__(16) unsigned short Plds[8][32 * 64];    // 32 KB
    const int tid = threadIdx.x, l = tid & 63, w = tid >> 6;     // 8 waves
    const int lr = l & 15, lg = l >> 4;
    const int bid = blockIdx.x;                 // 256 blocks, 1D
    const int sX = bid >> 3;                    // 0..31
    const int bh = (bid & 7) * 4 + (sX >> 3);   // XCD (bid&7) owns heads 4k..4k+3
    const int q0 = (sX & 7) * 256;
    const int b = bh >> 4, h = bh & 15;

    // Q fragments: 2 q-halves x 4 K-chunks (rows q0+w*32+qh*16+lr)
    i32x4 qf[2][4];
#pragma unroll
    for (int qh = 0; qh < 2; qh++) {
        const unsigned short* qbase =
            Q + (size_t)(b * SEQ + q0 + w * 32 + qh * 16 + lr) * HIDDEN + h * HDIM + lg * 8;
#pragma unroll
        for (int c = 0; c < 4; c++) qf[qh][c] = *(const i32x4*)(qbase + c * 32);
    }

    // staging: 2 K-chunks + 2 V-chunks per thread (512 threads), source pre-swizzled
    const unsigned short* kg[2];
    const unsigned short* vg[2];
    int kl[2], vl[2];
#pragma unroll
    for (int c = 0; c < 2; c++) {
        int cc = tid + c * 512;
        {   int row = cc >> 4, ch = cc & 15, sch = ch ^ (row & 7);
            kg[c] = K + (size_t)(b * SEQ + row) * HIDDEN + h * HDIM + sch * 8;
            kl[c] = cc * 8; }
        {   int row = cc >> 3, ch = cc & 7, sch = ch ^ (row & 7);
            vg[c] = Vt + (size_t)(bh * HDIM + row) * SEQ + sch * 8;
            vl[c] = cc * 8; }
    }

    auto stage = [&](int t, int bsel) {
        const size_t ko = (size_t)t * 64;
#pragma unroll
        for (int c = 0; c < 2; c++) {
            gl_lds16(kg[c] + ko * HIDDEN, &Klds[bsel][kl[c]]);
            gl_lds16(vg[c] + ko,          &Vlds[bsel][vl[c]]);
        }
    };

    f32x4 acc[2][8] = {};
    float m_run[2] = {-1e30f, -1e30f}, l_run[2] = {0.f, 0.f};

    stage(0, 0);
    const int nt = SEQ / 64;                // 32
    for (int t = 0; t < nt; ++t) {
        asm volatile("s_waitcnt vmcnt(0)" ::: "memory");
        __builtin_amdgcn_s_barrier();           // tile t staged, prev reads retired
        asm volatile("" ::: "memory");
        __builtin_amdgcn_sched_barrier(0);
        if (t + 1 < nt) stage(t + 1, (t + 1) & 1);
        const unsigned short* Kb_ = Klds[t & 1];
        const unsigned short* Vb_ = Vlds[t & 1];

        // swapped QK^T: kf loaded once per (ks,c), reused for both q-halves
        f32x4 s[4][2];
        __builtin_amdgcn_s_setprio(1);
#pragma unroll
        for (int ks = 0; ks < 4; ks++) {
            s[ks][0] = f32x4{0.f, 0.f, 0.f, 0.f};
            s[ks][1] = f32x4{0.f, 0.f, 0.f, 0.f};
#pragma unroll
            for (int c = 0; c < 4; c++) {
                i32x4 kf = *(const i32x4*)&Kb_[(ks * 16 + lr) * 128 + ((c * 4 + lg) ^ (lr & 7)) * 8];
                s[ks][0] = __builtin_amdgcn_mfma_f32_16x16x32_bf16(
                    __builtin_bit_cast(bf16x8, kf), __builtin_bit_cast(bf16x8, qf[0][c]),
                    s[ks][0], 0, 0, 0);
                s[ks][1] = __builtin_amdgcn_mfma_f32_16x16x32_bf16(
                    __builtin_bit_cast(bf16x8, kf), __builtin_bit_cast(bf16x8, qf[1][c]),
                    s[ks][1], 0, 0, 0);
            }
        }
        __builtin_amdgcn_s_setprio(0);

        // lane-local row softmax per q-half (exp2 domain; scale folded into WqT)
        float p[2][4][4];
        float fac[2];
        bool need_any = false;
#pragma unroll
        for (int qh = 0; qh < 2; qh++) {
            float mx0 = fmaxf(fmaxf(s[0][qh][0], s[0][qh][1]), fmaxf(s[0][qh][2], s[0][qh][3]));
            float mx1 = fmaxf(fmaxf(s[1][qh][0], s[1][qh][1]), fmaxf(s[1][qh][2], s[1][qh][3]));
            float mx2 = fmaxf(fmaxf(s[2][qh][0], s[2][qh][1]), fmaxf(s[2][qh][2], s[2][qh][3]));
            float mx3 = fmaxf(fmaxf(s[3][qh][0], s[3][qh][1]), fmaxf(s[3][qh][2], s[3][qh][3]));
            float pmax = fmaxf(fmaxf(mx0, mx1), fmaxf(mx2, mx3));
            pmax = fmaxf(pmax, __shfl_xor(pmax, 16));
            pmax = fmaxf(pmax, __shfl_xor(pmax, 32));
            bool need = pmax > m_run[qh] + 8.0f;     // defer-rescale (T13)
            fac[qh] = need ? __builtin_amdgcn_exp2f(m_run[qh] - pmax) : 1.0f;
            float mn = need ? pmax : m_run[qh];
            m_run[qh] = mn;
            float psum = 0.f;
#pragma unroll
            for (int ks = 0; ks < 4; ks++) {
                float e0 = __builtin_amdgcn_exp2f(s[ks][qh][0] - mn);
                float e1 = __builtin_amdgcn_exp2f(s[ks][qh][1] - mn);
                float e2 = __builtin_amdgcn_exp2f(s[ks][qh][2] - mn);
                float e3 = __builtin_amdgcn_exp2f(s[ks][qh][3] - mn);
                p[qh][ks][0] = e0; p[qh][ks][1] = e1;
                p[qh][ks][2] = e2; p[qh][ks][3] = e3;
                psum += (e0 + e1) + (e2 + e3);
            }
            psum += __shfl_xor(psum, 16);
            psum += __shfl_xor(psum, 32);
            l_run[qh] = l_run[qh] * fac[qh] + psum;
            need_any |= need;
        }

        // P -> wave-private LDS (involution swizzle, R12-verified mapping)
        unsigned short* pw = &Plds[w][0];
#pragma unroll
        for (int qh = 0; qh < 2; qh++)
#pragma unroll
            for (int ks = 0; ks < 4; ks++) {
                ushort4 pk;
                pk.x = f2bf(p[qh][ks][0]); pk.y = f2bf(p[qh][ks][1]);
                pk.z = f2bf(p[qh][ks][2]); pk.w = f2bf(p[qh][ks][3]);
                int chunk = ks * 2 + (lg >> 1);
                *(ushort4*)&pw[(qh * 16 + lr) * 64 + ((chunk ^ (lr & 7)) * 8) + (lg & 1) * 4] = pk;
            }

        if (__any((int)need_any)) {
#pragma unroll
            for (int qh = 0; qh < 2; qh++) {
                float facq[4];
#pragma unroll
                for (int r = 0; r < 4; r++) facq[r] = __shfl(fac[qh], lg * 4 + r);
#pragma unroll
                for (int db = 0; db < 8; db++)
#pragma unroll
                    for (int r = 0; r < 4; r++) acc[qh][db][r] *= facq[r];
            }
        }

        __builtin_amdgcn_s_setprio(1);
#pragma unroll
        for (int kk = 0; kk < 2; kk++) {
            i32x4 pf0 = *(const i32x4*)&pw[(lr) * 64 + ((kk * 4 + lg) ^ (lr & 7)) * 8];
            i32x4 pf1 = *(const i32x4*)&pw[(16 + lr) * 64 + ((kk * 4 + lg) ^ (lr & 7)) * 8];
#pragma unroll
            for (int db = 0; db < 8; db++) {
                i32x4 vf = *(const i32x4*)&Vb_[(db * 16 + lr) * 64 + ((kk * 4 + lg) ^ (lr & 7)) * 8];
                acc[0][db] = __builtin_amdgcn_mfma_f32_16x16x32_bf16(
                    __builtin_bit_cast(bf16x8, pf0), __builtin_bit_cast(bf16x8, vf),
                    acc[0][db], 0, 0, 0);
                acc[1][db] = __builtin_amdgcn_mfma_f32_16x16x32_bf16(
                    __builtin_bit_cast(bf16x8, pf1), __builtin_bit_cast(bf16x8, vf),
                    acc[1][db], 0, 0, 0);
            }
        }
        __builtin_amdgcn_s_setprio(0);
    }

#pragma unroll
    for (int qh = 0; qh < 2; qh++) {
        float inv[4];
#pragma unroll
        for (int r = 0; r < 4; r++) inv[r] = 1.0f / __shfl(l_run[qh], lg * 4 + r);
#pragma unroll
        for (int db = 0; db < 8; db++)
#pragma unroll
            for (int r = 0; r < 4; r++) {
                int trow = q0 + w * 32 + qh * 16 + lg * 4 + r;
                ctx[(size_t)(b * SEQ + trow) * HIDDEN + h * HDIM + db * 16 + lr] =
                    f2bf(acc[qh][db][r] * inv[r]);
            }
    }
}

extern "C" void kernel_launch(void* const* d_in, const int* in_sizes, int n_in,
                              void* d_out, int out_size, void* d_ws, size_t ws_size,
                              hipStream_t stream)
{
    (void)in_sizes; (void)n_in; (void)out_size; (void)ws_size;
    const float* X  = (const float*)d_in[0];
    const float* Wq = (const float*)d_in[1];
    const float* Wk = (const float*)d_in[2];
    const float* Wv = (const float*)d_in[3];
    const float* Wo = (const float*)d_in[4];
    float* out = (float*)d_out;
    char* ws = (char*)d_ws;

    unsigned short* Xb  = (unsigned short*)(ws);                 // 16 MB  (4096x2048 bf16)
    unsigned short* WqT = (unsigned short*)(ws + 16777216);      // 8 MB each, N x K bf16
    unsigned short* WkT = (unsigned short*)(ws + 25165824);
    unsigned short* WvT = (unsigned short*)(ws + 33554432);
    unsigned short* WoT = (unsigned short*)(ws + 41943040);
    unsigned short* Qb  = (unsigned short*)(ws + 50331648);      // 16 MB each
    unsigned short* Kb  = (unsigned short*)(ws + 67108864);
    unsigned short* Vt  = (unsigned short*)(ws + 100663296);     // V written transposed by GEMM
    unsigned short* Cx  = (unsigned short*)(ws + 117440512);
    float* ctab = (float*)(ws + 134217728);                      // 0.5 MB each
    float* stab = (float*)(ws + 134742016);

    k_cvt_tables<<<8704, 256, 0, stream>>>(X, Xb, ctab, stab);
    k_transcvt4<<<dim3(64, 64, 4), dim3(32, 8), 0, stream>>>(Wq, Wk, Wv, Wo,
                                                             WqT, WkT, WvT, WoT);
    k_gemm256<1><<<768, 512, 0, stream>>>(Xb, WqT, WkT, WvT, Qb, Kb, Vt,
                                          ctab, stab, 2048);
    k_attn<<<256, 512, 0, stream>>>(Qb, Kb, Vt, Cx);
    k_gemm256<0><<<256, 512, 0, stream>>>(Cx, WoT, WoT, WoT, out, out, out,
                                          nullptr, nullptr, 2048);
}

// Round 17
// 258.942 us; speedup vs baseline: 1.1458x; 1.0096x over previous
//
#include <hip/hip_runtime.h>

#define HIDDEN 2048
#define SEQ    2048
#define BATCH  2
#define NHEAD  16
#define HDIM   128

typedef __attribute__((ext_vector_type(4))) int    i32x4;
typedef __attribute__((ext_vector_type(4))) float  f32x4;
typedef __attribute__((ext_vector_type(8))) __bf16 bf16x8;

__device__ __forceinline__ unsigned short f2bf(float f) {
    return __builtin_bit_cast(unsigned short, (__bf16)f);   // hw RNE cvt
}
__device__ __forceinline__ float bf2f(unsigned short h) {
    unsigned u = ((unsigned)h) << 16;
    return __builtin_bit_cast(float, u);
}
// async global->LDS, 16B per lane; dest must be wave-uniform base + lane*16
__device__ __forceinline__ void gl_lds16(const unsigned short* g, unsigned short* l) {
    __builtin_amdgcn_global_load_lds(
        (const __attribute__((address_space(1))) unsigned int*)g,
        (__attribute__((address_space(3))) unsigned int*)l, 16, 0, 0);
}

// ---------------- unified prep: W^T-convert (0..16383), X cvt (16384..24575),
// RoPE tables (24576..25087). One dispatch replaces three.
__global__ void k_prep(const float* __restrict__ X, unsigned short* __restrict__ Xb,
                       float* __restrict__ ctab, float* __restrict__ stab,
                       const float* __restrict__ W0, const float* __restrict__ W1,
                       const float* __restrict__ W2, const float* __restrict__ W3,
                       unsigned short* __restrict__ O0, unsigned short* __restrict__ O1,
                       unsigned short* __restrict__ O2, unsigned short* __restrict__ O3)
{
    __shared__ float tile[32][33];
    int bid = blockIdx.x, tid = threadIdx.x;
    if (bid < 16384) {
        // W (K x N fp32) -> W^T (N x K bf16); z==0 (Wq) pre-scaled by log2(e)/sqrt(D)
        int z = bid >> 12, rem = bid & 4095;
        int by = rem >> 6, bx = rem & 63;
        const float* in = (z == 0) ? W0 : (z == 1) ? W1 : (z == 2) ? W2 : W3;
        unsigned short* out = (z == 0) ? O0 : (z == 1) ? O1 : (z == 2) ? O2 : O3;
        float scl = (z == 0) ? 0.12751743f : 1.0f;
        int tx = tid & 31, ty = tid >> 5;
        int x = bx * 32 + tx, y0 = by * 32;
#pragma unroll
        for (int i = 0; i < 4; i++)
            tile[ty + i * 8][tx] = in[(size_t)(y0 + ty + i * 8) * HIDDEN + x];
        __syncthreads();
        int x2 = by * 32 + tx, y2 = bx * 32;
#pragma unroll
        for (int i = 0; i < 4; i++)
            out[(size_t)(y2 + ty + i * 8) * HIDDEN + x2] = f2bf(tile[tx][ty + i * 8] * scl);
    } else if (bid < 24576) {
        int idx = (bid - 16384) * 256 + tid;
        float4 v = ((const float4*)X)[idx];
        ushort4 o;
        o.x = f2bf(v.x); o.y = f2bf(v.y); o.z = f2bf(v.z); o.w = f2bf(v.w);
        ((ushort4*)Xb)[idx] = o;
    } else {
        int idx = (bid - 24576) * 256 + tid;           // SEQ*64 entries
        int t = idx >> 6, i = idx & 63;
        float inv = expf(-(float)i * 0.14391156831212793f);  // ln(10000)/64
        float ang = (float)t * inv;
        ctab[idx] = cosf(ang);
        stab[idx] = sinf(ang);
    }
}

// ---------------- 256x128-tile bf16 GEMM, 8 waves x (64x64), triple-buffer LDS,
// counted vmcnt(6)  [R9-proven main loop: 0 bank conflicts, MfmaUtil 38.8%].
// Epilogues: z==2 writes V transposed into Vt[bh][d][t] (R15-proven);
// z<=1 (Q,K) apply RoPE in fp32 before the bf16 write (R16-proven).
template <int OUTB>
__global__ __launch_bounds__(512, 1) void k_gemm256(
    const unsigned short* __restrict__ A,
    const unsigned short* __restrict__ B0, const unsigned short* __restrict__ B1,
    const unsigned short* __restrict__ B2,
    void* __restrict__ C0, void* __restrict__ C1, void* __restrict__ C2,
    const float* __restrict__ ctab, const float* __restrict__ stab,
    int K)
{
    __shared__ __align__(16) unsigned short S[3 * 24576];   // 144 KB
    const int nwg = gridDim.x;                               // 768 or 256, %8==0
    int id = blockIdx.x;
    int wg = (id & 7) * (nwg >> 3) + (id >> 3);              // XCD-aware swizzle (T1)
    const int z = wg >> 8;                                   // 16x16 blocks per z
    const int my = (wg >> 4) & 15, nx = wg & 15;
    const unsigned short* Bm = (z == 0) ? B0 : (z == 1 ? B1 : B2);
    void* Cv = (z == 0) ? C0 : (z == 1 ? C1 : C2);
    const int m0 = my * 256, n0 = nx * 128;
    const int tid = threadIdx.x, l = tid & 63, w = tid >> 6;
    const int wm = w >> 1, wn = w & 1;                       // 4 M-waves x 2 N-waves
    const int lr = l & 15, lg = l >> 4;

    const unsigned short* sg[6];
    int so[6];
#pragma unroll
    for (int j = 0; j < 4; j++) {
        int c = tid + j * 512, row = c >> 3, k8 = c & 7;
        sg[j] = A + (size_t)(m0 + row) * K + ((k8 ^ (row & 7)) * 8);
        so[j] = row * 64 + k8 * 8;
    }
#pragma unroll
    for (int j = 0; j < 2; j++) {
        int c = tid + j * 512, row = c >> 3, k8 = c & 7;
        sg[4 + j] = Bm + (size_t)(n0 + row) * K + ((k8 ^ (row & 7)) * 8);
        so[4 + j] = 16384 + row * 64 + k8 * 8;
    }

    f32x4 acc[4][4] = {};

    auto stage = [&](int t) {
        unsigned short* buf = &S[(t % 3) * 24576];
        const int ko = t * 64;
#pragma unroll
        for (int j = 0; j < 6; j++) gl_lds16(sg[j] + ko, &buf[so[j]]);
    };
    auto compute = [&](int t) {
        const unsigned short* buf = &S[(t % 3) * 24576];
        const unsigned short* bb = buf + 16384;
        const int xk0 = (lg ^ (lr & 7)) * 8, xk1 = ((4 + lg) ^ (lr & 7)) * 8;
        i32x4 af0[4], af1[4], bf0[4], bf1[4];
#pragma unroll
        for (int i = 0; i < 4; i++) {
            int R = (wm * 64 + i * 16 + lr) * 64;
            af0[i] = *(const i32x4*)&buf[R + xk0];
            af1[i] = *(const i32x4*)&buf[R + xk1];
        }
#pragma unroll
        for (int j = 0; j < 4; j++) {
            int R = (wn * 64 + j * 16 + lr) * 64;
            bf0[j] = *(const i32x4*)&bb[R + xk0];
            bf1[j] = *(const i32x4*)&bb[R + xk1];
        }
        __builtin_amdgcn_s_setprio(1);
#pragma unroll
        for (int i = 0; i < 4; i++)
#pragma unroll
            for (int j = 0; j < 4; j++)
                acc[i][j] = __builtin_amdgcn_mfma_f32_16x16x32_bf16(
                    __builtin_bit_cast(bf16x8, af0[i]),
                    __builtin_bit_cast(bf16x8, bf0[j]), acc[i][j], 0, 0, 0);
#pragma unroll
        for (int i = 0; i < 4; i++)
#pragma unroll
            for (int j = 0; j < 4; j++)
                acc[i][j] = __builtin_amdgcn_mfma_f32_16x16x32_bf16(
                    __builtin_bit_cast(bf16x8, af1[i]),
                    __builtin_bit_cast(bf16x8, bf1[j]), acc[i][j], 0, 0, 0);
        __builtin_amdgcn_s_setprio(0);
    };

    const int nt = K / 64;                 // 32
    stage(0); stage(1);                    // 12 loads in flight
    for (int t = 0; t < nt - 1; ++t) {
        asm volatile("s_waitcnt vmcnt(6)" ::: "memory");
        __builtin_amdgcn_s_barrier();
        __builtin_amdgcn_sched_barrier(0);
        if (t < nt - 2) stage(t + 2);
        compute(t);
    }
    asm volatile("s_waitcnt vmcnt(0)" ::: "memory");
    __builtin_amdgcn_s_barrier();
    __builtin_amdgcn_sched_barrier(0);
    compute(nt - 1);

    if (OUTB && z == 2) {
        // V: write transposed Vt[(b*2048 + n)][t], t = m & 2047, b = m >> 11
        unsigned short* Vt = (unsigned short*)Cv;
        const int bb_ = m0 >> 11;
        const int tb = (m0 & 2047) + wm * 64;
#pragma unroll
        for (int i = 0; i < 4; i++)
#pragma unroll
            for (int j = 0; j < 4; j++) {
                int t0 = tb + i * 16 + lg * 4;
                int n = n0 + wn * 64 + j * 16 + lr;
                ushort4 pk;
                pk.x = f2bf(acc[i][j][0]); pk.y = f2bf(acc[i][j][1]);
                pk.z = f2bf(acc[i][j][2]); pk.w = f2bf(acc[i][j][3]);
                *(ushort4*)&Vt[((size_t)(bb_ * 2048 + n)) * 2048 + t0] = pk;
            }
    } else if (OUTB) {
        // Q/K: fused RoPE.  d = wn*64 + j*16 + lr; prev = x[(d-1)&127]:
        //  lr>0: shfl(acc[i][j][r], l-1);  lr==0,j>0: shfl(acc[i][j-1][r], lg*16+15)
        //  lr==0,j==0: partner wave (wn^1) [i][3][r]@lr15 via LDS (d=127<->63 wrap)
        float* xch = (float*)S;        // 512 floats; buf0 reads retired pre-final-barrier
        if (lr == 15) {
#pragma unroll
            for (int i = 0; i < 4; i++)
#pragma unroll
                for (int r = 0; r < 4; r++)
                    xch[(((wm << 1) | wn) * 4 + i) * 16 + lg * 4 + r] = acc[i][3][r];
        }
        __syncthreads();
        unsigned short* Co = (unsigned short*)Cv;
#pragma unroll
        for (int i = 0; i < 4; i++)
#pragma unroll
            for (int r = 0; r < 4; r++) {
                int m = m0 + wm * 64 + i * 16 + lg * 4 + r;
                int t = m & 2047;
                float ldsprev = xch[(((wm << 1) | (wn ^ 1)) * 4 + i) * 16 + lg * 4 + r];
#pragma unroll
                for (int j = 0; j < 4; j++) {
                    float v = acc[i][j][r];
                    float pA = __shfl(v, l - 1);
                    float prev;
                    if (j == 0) {
                        prev = (lr == 0) ? ldsprev : pA;
                    } else {
                        float pB = __shfl(acc[i][j - 1][r], (l & 48) + 15);
                        prev = (lr == 0) ? pB : pA;
                    }
                    float cc = ctab[t * 64 + j * 16 + lr];
                    float ss = stab[t * 64 + j * 16 + lr];
                    int n = n0 + wn * 64 + j * 16 + lr;
                    Co[(size_t)m * 2048 + n] = f2bf(v * cc + prev * ss);
                }
            }
    } else {
#pragma unroll
        for (int i = 0; i < 4; i++)
#pragma unroll
            for (int j = 0; j < 4; j++)
#pragma unroll
                for (int r = 0; r < 4; r++) {
                    int m = m0 + wm * 64 + i * 16 + lg * 4 + r;
                    int n = n0 + wn * 64 + j * 16 + lr;
                    ((float*)Cv)[(size_t)m * 2048 + n] = acc[i][j][r];
                }
    }
}

// ---------------- flash attention: swapped-QK^T, 8 waves x 32 q-rows = 256 q/block.
// K/V now TRIPLE-buffered with counted vmcnt(4) (R9 GEMM ledger transplanted):
// iter t: vmcnt(4) certifies tile t (t+1's 4 loads stay in flight across barrier);
// stage(t+2) overwrites buf(t-1) whose ds_reads completed before this barrier.
__global__ __launch_bounds__(512) void k_attn(
    const unsigned short* __restrict__ Q, const unsigned short* __restrict__ K,
    const unsigned short* __restrict__ Vt, unsigned short* __restrict__ ctx)
{
    __shared__ __align__(16) unsigned short Klds[3][64 * 128];   // 48 KB
    __shared__ __align__(16) unsigned short Vlds[3][128 * 64];   // 48 KB
    __shared__ __align__(16) unsigned short Plds[8][32 * 64];    // 32 KB
    const int tid = threadIdx.x, l = tid & 63, w = tid >> 6;     // 8 waves
    const int lr = l & 15, lg = l >> 4;
    const int bid = blockIdx.x;                 // 256 blocks, 1D
    const int sX = bid >> 3;                    // 0..31
    const int bh = (bid & 7) * 4 + (sX >> 3);   // XCD (bid&7) owns heads 4k..4k+3
    const int q0 = (sX & 7) * 256;
    const int b = bh >> 4, h = bh & 15;

    // Q fragments: 2 q-halves x 4 K-chunks (rows q0+w*32+qh*16+lr)
    i32x4 qf[2][4];
#pragma unroll
    for (int qh = 0; qh < 2; qh++) {
        const unsigned short* qbase =
            Q + (size_t)(b * SEQ + q0 + w * 32 + qh * 16 + lr) * HIDDEN + h * HDIM + lg * 8;
#pragma unroll
        for (int c = 0; c < 4; c++) qf[qh][c] = *(const i32x4*)(qbase + c * 32);
    }

    // staging: 2 K-chunks + 2 V-chunks per thread (512 threads), source pre-swizzled
    const unsigned short* kg[2];
    const unsigned short* vg[2];
    int kl[2], vl[2];
#pragma unroll
    for (int c = 0; c < 2; c++) {
        int cc = tid + c * 512;
        {   int row = cc >> 4, ch = cc & 15, sch = ch ^ (row & 7);
            kg[c] = K + (size_t)(b * SEQ + row) * HIDDEN + h * HDIM + sch * 8;
            kl[c] = cc * 8; }
        {   int row = cc >> 3, ch = cc & 7, sch = ch ^ (row & 7);
            vg[c] = Vt + (size_t)(bh * HDIM + row) * SEQ + sch * 8;
            vl[c] = cc * 8; }
    }

    auto stage = [&](int t) {
        const int bsel = t % 3;
        const size_t ko = (size_t)t * 64;
#pragma unroll
        for (int c = 0; c < 2; c++) {
            gl_lds16(kg[c] + ko * HIDDEN, &Klds[bsel][kl[c]]);
            gl_lds16(vg[c] + ko,          &Vlds[bsel][vl[c]]);
        }
    };

    f32x4 acc[2][8] = {};
    float m_run[2] = {-1e30f, -1e30f}, l_run[2] = {0.f, 0.f};

    stage(0); stage(1);                     // 8 loads in flight
    const int nt = SEQ / 64;                // 32
    for (int t = 0; t < nt; ++t) {
        if (t + 1 < nt) { asm volatile("s_waitcnt vmcnt(4)" ::: "memory"); }
        else            { asm volatile("s_waitcnt vmcnt(0)" ::: "memory"); }
        __builtin_amdgcn_s_barrier();           // tile t certified; buf(t-1) dead
        __builtin_amdgcn_sched_barrier(0);
        if (t + 2 < nt) stage(t + 2);
        const unsigned short* Kb_ = Klds[t % 3];
        const unsigned short* Vb_ = Vlds[t % 3];

        // swapped QK^T: kf loaded once per (ks,c), reused for both q-halves
        f32x4 s[4][2];
        __builtin_amdgcn_s_setprio(1);
#pragma unroll
        for (int ks = 0; ks < 4; ks++) {
            s[ks][0] = f32x4{0.f, 0.f, 0.f, 0.f};
            s[ks][1] = f32x4{0.f, 0.f, 0.f, 0.f};
#pragma unroll
            for (int c = 0; c < 4; c++) {
                i32x4 kf = *(const i32x4*)&Kb_[(ks * 16 + lr) * 128 + ((c * 4 + lg) ^ (lr & 7)) * 8];
                s[ks][0] = __builtin_amdgcn_mfma_f32_16x16x32_bf16(
                    __builtin_bit_cast(bf16x8, kf), __builtin_bit_cast(bf16x8, qf[0][c]),
                    s[ks][0], 0, 0, 0);
                s[ks][1] = __builtin_amdgcn_mfma_f32_16x16x32_bf16(
                    __builtin_bit_cast(bf16x8, kf), __builtin_bit_cast(bf16x8, qf[1][c]),
                    s[ks][1], 0, 0, 0);
            }
        }
        __builtin_amdgcn_s_setprio(0);

        // lane-local row softmax per q-half (exp2 domain; scale folded into WqT)
        float p[2][4][4];
        float fac[2];
        bool need_any = false;
#pragma unroll
        for (int qh = 0; qh < 2; qh++) {
            float mx0 = fmaxf(fmaxf(s[0][qh][0], s[0][qh][1]), fmaxf(s[0][qh][2], s[0][qh][3]));
            float mx1 = fmaxf(fmaxf(s[1][qh][0], s[1][qh][1]), fmaxf(s[1][qh][2], s[1][qh][3]));
            float mx2 = fmaxf(fmaxf(s[2][qh][0], s[2][qh][1]), fmaxf(s[2][qh][2], s[2][qh][3]));
            float mx3 = fmaxf(fmaxf(s[3][qh][0], s[3][qh][1]), fmaxf(s[3][qh][2], s[3][qh][3]));
            float pmax = fmaxf(fmaxf(mx0, mx1), fmaxf(mx2, mx3));
            pmax = fmaxf(pmax, __shfl_xor(pmax, 16));
            pmax = fmaxf(pmax, __shfl_xor(pmax, 32));
            bool need = pmax > m_run[qh] + 8.0f;     // defer-rescale (T13)
            fac[qh] = need ? __builtin_amdgcn_exp2f(m_run[qh] - pmax) : 1.0f;
            float mn = need ? pmax : m_run[qh];
            m_run[qh] = mn;
            float psum = 0.f;
#pragma unroll
            for (int ks = 0; ks < 4; ks++) {
                float e0 = __builtin_amdgcn_exp2f(s[ks][qh][0] - mn);
                float e1 = __builtin_amdgcn_exp2f(s[ks][qh][1] - mn);
                float e2 = __builtin_amdgcn_exp2f(s[ks][qh][2] - mn);
                float e3 = __builtin_amdgcn_exp2f(s[ks][qh][3] - mn);
                p[qh][ks][0] = e0; p[qh][ks][1] = e1;
                p[qh][ks][2] = e2; p[qh][ks][3] = e3;
                psum += (e0 + e1) + (e2 + e3);
            }
            psum += __shfl_xor(psum, 16);
            psum += __shfl_xor(psum, 32);
            l_run[qh] = l_run[qh] * fac[qh] + psum;
            need_any |= need;
        }

        // P -> wave-private LDS (involution swizzle, R12-verified mapping)
        unsigned short* pw = &Plds[w][0];
#pragma unroll
        for (int qh = 0; qh < 2; qh++)
#pragma unroll
            for (int ks = 0; ks < 4; ks++) {
                ushort4 pk;
                pk.x = f2bf(p[qh][ks][0]); pk.y = f2bf(p[qh][ks][1]);
                pk.z = f2bf(p[qh][ks][2]); pk.w = f2bf(p[qh][ks][3]);
                int chunk = ks * 2 + (lg >> 1);
                *(ushort4*)&pw[(qh * 16 + lr) * 64 + ((chunk ^ (lr & 7)) * 8) + (lg & 1) * 4] = pk;
            }

        if (__any((int)need_any)) {
#pragma unroll
            for (int qh = 0; qh < 2; qh++) {
                float facq[4];
#pragma unroll
                for (int r = 0; r < 4; r++) facq[r] = __shfl(fac[qh], lg * 4 + r);
#pragma unroll
                for (int db = 0; db < 8; db++)
#pragma unroll
                    for (int r = 0; r < 4; r++) acc[qh][db][r] *= facq[r];
            }
        }

        __builtin_amdgcn_s_setprio(1);
#pragma unroll
        for (int kk = 0; kk < 2; kk++) {
            i32x4 pf0 = *(const i32x4*)&pw[(lr) * 64 + ((kk * 4 + lg) ^ (lr & 7)) * 8];
            i32x4 pf1 = *(const i32x4*)&pw[(16 + lr) * 64 + ((kk * 4 + lg) ^ (lr & 7)) * 8];
#pragma unroll
            for (int db = 0; db < 8; db++) {
                i32x4 vf = *(const i32x4*)&Vb_[(db * 16 + lr) * 64 + ((kk * 4 + lg) ^ (lr & 7)) * 8];
                acc[0][db] = __builtin_amdgcn_mfma_f32_16x16x32_bf16(
                    __builtin_bit_cast(bf16x8, pf0), __builtin_bit_cast(bf16x8, vf),
                    acc[0][db], 0, 0, 0);
                acc[1][db] = __builtin_amdgcn_mfma_f32_16x16x32_bf16(
                    __builtin_bit_cast(bf16x8, pf1), __builtin_bit_cast(bf16x8, vf),
                    acc[1][db], 0, 0, 0);
            }
        }
        __builtin_amdgcn_s_setprio(0);
    }

#pragma unroll
    for (int qh = 0; qh < 2; qh++) {
        float inv[4];
#pragma unroll
        for (int r = 0; r < 4; r++) inv[r] = 1.0f / __shfl(l_run[qh], lg * 4 + r);
#pragma unroll
        for (int db = 0; db < 8; db++)
#pragma unroll
            for (int r = 0; r < 4; r++) {
                int trow = q0 + w * 32 + qh * 16 + lg * 4 + r;
                ctx[(size_t)(b * SEQ + trow) * HIDDEN + h * HDIM + db * 16 + lr] =
                    f2bf(acc[qh][db][r] * inv[r]);
            }
    }
}

extern "C" void kernel_launch(void* const* d_in, const int* in_sizes, int n_in,
                              void* d_out, int out_size, void* d_ws, size_t ws_size,
                              hipStream_t stream)
{
    (void)in_sizes; (void)n_in; (void)out_size; (void)ws_size;
    const float* X  = (const float*)d_in[0];
    const float* Wq = (const float*)d_in[1];
    const float* Wk = (const float*)d_in[2];
    const float* Wv = (const float*)d_in[3];
    const float* Wo = (const float*)d_in[4];
    float* out = (float*)d_out;
    char* ws = (char*)d_ws;

    unsigned short* Xb  = (unsigned short*)(ws);                 // 16 MB  (4096x2048 bf16)
    unsigned short* WqT = (unsigned short*)(ws + 16777216);      // 8 MB each, N x K bf16
    unsigned short* WkT = (unsigned short*)(ws + 25165824);
    unsigned short* WvT = (unsigned short*)(ws + 33554432);
    unsigned short* WoT = (unsigned short*)(ws + 41943040);
    unsigned short* Qb  = (unsigned short*)(ws + 50331648);      // 16 MB each
    unsigned short* Kb  = (unsigned short*)(ws + 67108864);
    unsigned short* Vt  = (unsigned short*)(ws + 100663296);     // V written transposed by GEMM
    unsigned short* Cx  = (unsigned short*)(ws + 117440512);
    float* ctab = (float*)(ws + 134217728);                      // 0.5 MB each
    float* stab = (float*)(ws + 134742016);

    k_prep<<<25088, 256, 0, stream>>>(X, Xb, ctab, stab, Wq, Wk, Wv, Wo,
                                      WqT, WkT, WvT, WoT);
    k_gemm256<1><<<768, 512, 0, stream>>>(Xb, WqT, WkT, WvT, Qb, Kb, Vt,
                                          ctab, stab, 2048);
    k_attn<<<256, 512, 0, stream>>>(Qb, Kb, Vt, Cx);
    k_gemm256<0><<<256, 512, 0, stream>>>(Cx, WoT, WoT, WoT, out, out, out,
                                          nullptr, nullptr, 2048);
}